// Round 16
// baseline (461.131 us; speedup 1.0000x reference)
//
#include <hip/hip_runtime.h>

typedef __attribute__((ext_vector_type(8))) short bf16x8;
typedef __attribute__((ext_vector_type(4))) float f32x4;

constexpr int NCH = 18;     // 32-k chunks per K-quarter (K = 2304 symmetrized)
constexpr int REPS = 4;     // probe repetitions (reps 0..2 contribute exact zeros)

__device__ __forceinline__ unsigned short bf_rne(float f) {
  unsigned u = __float_as_uint(f);
  return (unsigned short)((u + 0x7fffu + ((u >> 16) & 1u)) >> 16);
}

// ---- prepass (COALESCED rewrite): one o-row per block via LDS ----
// Old version gathered with 16KB lane stride (64 lines per wave-load).
// Same output as r5-r15 (verified layout): Wp[(kq*18+j)*2048 + nt*512 + (q*16+r16)*8 + el]
__global__ __launch_bounds__(256) void wprep_kernel(const float* __restrict__ W,
                                                    unsigned short* __restrict__ Wp) {
  __shared__ float L[4096];                 // one W row (o fixed), 16 KB
  const int o = blockIdx.x;                 // 0..63
  const int t = threadIdx.x;
  const float4* src = reinterpret_cast<const float4*>(W + o * 4096);
#pragma unroll
  for (int c = 0; c < 4; ++c)
    *reinterpret_cast<float4*>(&L[(c * 256 + t) * 4]) = src[c * 256 + t];
  __syncthreads();
  const int nt = o >> 4, r16 = o & 15;
#pragma unroll
  for (int kk = t; kk < 2304; kk += 256) {  // exactly 9 iters
    int kq = kk / 576;
    int kl = kk - kq * 576;
    int j = kl >> 5;
    int q = (kl >> 3) & 3;
    int el = kl & 7;
    int jblk = kl >> 6, i = kl & 63;
    int run1 = 8 - kq;
    int G, F;
    if (jblk < run1) { G = 7 - kq; F = jblk; } else { G = kq; F = jblk - run1; }
    int f = F * 8 + (i >> 3), g = G * 8 + (i & 7);
    float v = L[f * 64 + g];
    if (F != G) v += L[g * 64 + f];
    Wp[(kq * 18 + j) * 2048 + nt * 512 + (q * 16 + r16) * 8 + el] = bf_rne(v);
  }
}

// ================= shared quad body (r15 structure, verbatim) =================
// TAKE_REPS=1 -> plain production quad. TAKE_REPS=REPS -> probe: reps 0..R-2
// scale A-fragments by srep=0.0 (runtime) -> exact-zero accumulation, identical
// instruction stream per rep, acc stays in AGPRs (no keep-alive perturbation).
template <int TAKE_REPS>
__device__ __forceinline__ void quad_body(const float* __restrict__ x,
                                          const unsigned short* __restrict__ Wp,
                                          float* __restrict__ out,
                                          float* xT, float* red) {
  const int t = threadIdx.x;
  const int lane = t & 63;
  const int wv = t >> 6;
  const int kq = wv & 3;
  const int ph = wv >> 2;
  const int q = lane >> 4;
  const int r16 = lane & 15;
  const int pxbase = blockIdx.x * 128;

  int jbase = blockIdx.x % NCH + ph * (NCH / 2);
  if (jbase >= NCH) jbase -= NCH;

  const char* wsrc = reinterpret_cast<const char*>(Wp) + kq * 73728 + lane * 16;
  const int run1 = 8 - kq;
  auto Gof = [&](int je) { return ((je >> 1) < run1) ? (7 - kq) : kq; };

  bf16x8 bufs[4][4];
  auto loadB = [&](int je, int slot) {
#pragma unroll
    for (int nt = 0; nt < 4; ++nt)
      bufs[slot][nt] = *reinterpret_cast<const bf16x8*>(wsrc + je * 4096 + nt * 1024);
  };

  f32x4 acc[4][4] = {};

#pragma unroll 1
  for (int rep = 0; rep < TAKE_REPS; ++rep) {
    const float srep = (rep == TAKE_REPS - 1) ? 1.0f : 0.0f;   // runtime, no DCE

    {
      int je = jbase;
      loadB(je, 0); je = (je + 1 == NCH) ? 0 : je + 1;
      loadB(je, 1); je = (je + 1 == NCH) ? 0 : je + 1;
      loadB(je, 2);
    }

    __syncthreads();   // WAR: previous rep's xT readers done (no-op effect rep 0)
    {
      const float* xg_ = x + (long)pxbase * 64;
#pragma unroll
      for (int c = 0; c < 4; ++c) {
        int e4 = c * 512 + t;
        int px = e4 >> 4;
        int f0 = (e4 & 15) * 4;
        float4 v = *reinterpret_cast<const float4*>(xg_ + e4 * 4);
        xT[(f0 + 0) * 128 + (px ^ (f0 + 0))] = v.x;
        xT[(f0 + 1) * 128 + (px ^ (f0 + 1))] = v.y;
        xT[(f0 + 2) * 128 + (px ^ (f0 + 2))] = v.z;
        xT[(f0 + 3) * 128 + (px ^ (f0 + 3))] = v.w;
      }
    }
    __syncthreads();

    float xg[4][8];
    auto load_xg = [&](int G) {
#pragma unroll
      for (int m = 0; m < 4; ++m) {
        int px = ph * 64 + m * 16 + r16;
#pragma unroll
        for (int b = 0; b < 8; ++b) {
          int row = G * 8 + b;
          xg[m][b] = xT[row * 128 + (px ^ row)];
        }
      }
    };
    int curG = Gof(jbase);
    load_xg(curG);

    int je = jbase;
#pragma unroll
    for (int j = 0; j < NCH; ++j) {
      {
        int jp = je + 3;
        if (jp >= NCH) jp -= NCH;
        if (j + 3 < NCH) loadB(jp, (j + 3) & 3);
      }
      int G = Gof(je);
      if (G != curG) { curG = G; load_xg(G); }
      const int s = je & 1;
      const int blk = je >> 1;
      const int F = (blk < run1) ? blk : blk - run1;
      const int row = F * 8 + s * 4 + q;
      const int slot = j & 3;
      bf16x8 afr[4];
#pragma unroll
      for (int m = 0; m < 4; ++m) {
        float xf = xT[row * 128 + ((ph * 64 + m * 16 + r16) ^ row)] * srep;
        union { unsigned u[4]; bf16x8 v; } pk;
#pragma unroll
        for (int i = 0; i < 4; ++i) {
          unsigned p0 = __float_as_uint(xf * xg[m][2 * i]);
          unsigned p1 = __float_as_uint(xf * xg[m][2 * i + 1]);
          pk.u[i] = __builtin_amdgcn_perm(p1, p0, 0x07060302u);
        }
        afr[m] = pk.v;
      }
#pragma unroll
      for (int nt = 0; nt < 4; ++nt)
#pragma unroll
        for (int m = 0; m < 4; ++m)
          acc[m][nt] = __builtin_amdgcn_mfma_f32_16x16x32_bf16(afr[m], bufs[slot][nt],
                                                               acc[m][nt], 0, 0, 0);
      je = (je + 1 == NCH) ? 0 : je + 1;
    }
  }

  // ---- cross-kq reduction (verbatim r8): 2 rounds of m-pairs ----
  __syncthreads();
#pragma unroll
  for (int r = 0; r < 2; ++r) {
    if (r) __syncthreads();
#pragma unroll
    for (int mm = 0; mm < 2; ++mm)
#pragma unroll
      for (int nt = 0; nt < 4; ++nt)
        *reinterpret_cast<f32x4*>(red + ((ph * 2 + mm) * 4 + kq) * 1024 +
                                  (nt * 16 + r16) * 16 + q * 4) = acc[2 * r + mm][nt];
    __syncthreads();
    {
      const int mm2 = kq >> 1;
      const int h = kq & 1;
      const float* base = red + (ph * 2 + mm2) * 4 * 1024;
#pragma unroll
      for (int nh = 0; nh < 2; ++nh) {
        int nt = h * 2 + nh;
        int off = (nt * 16 + r16) * 16 + q * 4;
        f32x4 ssum = *reinterpret_cast<const f32x4*>(base + off);
#pragma unroll
        for (int w = 1; w < 4; ++w)
          ssum += *reinterpret_cast<const f32x4*>(base + w * 1024 + off);
        long prow = pxbase + ph * 64 + (2 * r + mm2) * 16 + q * 4;
#pragma unroll
        for (int b = 0; b < 4; ++b)
          out[(prow + b) * 64 + nt * 16 + r16] = ssum[b];
      }
    }
  }
}

__global__ __launch_bounds__(512) __attribute__((amdgpu_waves_per_eu(2, 2)))
void quad_kernel(const float* __restrict__ x, const unsigned short* __restrict__ Wp,
                 float* __restrict__ out) {
  __shared__ float xT[8192];
  __shared__ alignas(16) float red[16384];
  quad_body<1>(x, Wp, out, xT, red);
}

// PROBE: 4 reps, first 3 accumulate exact zeros -> same output, honest codegen,
// ~71 us dispatch (tops the harness fills -> real counters in top-5).
__global__ __launch_bounds__(512) __attribute__((amdgpu_waves_per_eu(2, 2)))
void quad_rep(const float* __restrict__ x, const unsigned short* __restrict__ Wp,
              float* __restrict__ out) {
  __shared__ float xT[8192];
  __shared__ alignas(16) float red[16384];
  quad_body<REPS>(x, Wp, out, xT, red);
}

extern "C" void kernel_launch(void* const* d_in, const int* in_sizes, int n_in,
                              void* d_out, int out_size, void* d_ws, size_t ws_size,
                              hipStream_t stream) {
  const float* x = (const float*)d_in[0];
  const float* W = (const float*)d_in[1];
  float* out = (float*)d_out;
  unsigned short* Wp = (unsigned short*)d_ws;   // 288 KB packed fragment-linear bf16 W

  hipLaunchKernelGGL(wprep_kernel, dim3(64), dim3(256), 0, stream, W, Wp);
  hipLaunchKernelGGL(quad_rep, dim3(256), dim3(512), 0, stream, x, Wp, out);     // probe
  hipLaunchKernelGGL(quad_kernel, dim3(256), dim3(512), 0, stream, x, Wp, out);  // truth
}

// Round 17
// 106.955 us; speedup vs baseline: 4.3114x; 4.3114x over previous
//
#include <hip/hip_runtime.h>

typedef __attribute__((ext_vector_type(8))) short bf16x8;
typedef __attribute__((ext_vector_type(4))) float f32x4;

constexpr int NCH = 18;     // 32-k chunks per K-quarter (K = 2304 symmetrized)
constexpr int DUP = 8;      // grid-duplication factor (probe; duplicates bit-identical)

__device__ __forceinline__ unsigned short bf_rne(float f) {
  unsigned u = __float_as_uint(f);
  return (unsigned short)((u + 0x7fffu + ((u >> 16) & 1u)) >> 16);
}

// ---- prepass (coalesced, r16): one o-row per block via LDS ----
__global__ __launch_bounds__(256) void wprep_kernel(const float* __restrict__ W,
                                                    unsigned short* __restrict__ Wp) {
  __shared__ float L[4096];                 // one W row (o fixed), 16 KB
  const int o = blockIdx.x;                 // 0..63
  const int t = threadIdx.x;
  const float4* src = reinterpret_cast<const float4*>(W + o * 4096);
#pragma unroll
  for (int c = 0; c < 4; ++c)
    *reinterpret_cast<float4*>(&L[(c * 256 + t) * 4]) = src[c * 256 + t];
  __syncthreads();
  const int nt = o >> 4, r16 = o & 15;
#pragma unroll
  for (int kk = t; kk < 2304; kk += 256) {  // exactly 9 iters
    int kq = kk / 576;
    int kl = kk - kq * 576;
    int j = kl >> 5;
    int q = (kl >> 3) & 3;
    int el = kl & 7;
    int jblk = kl >> 6, i = kl & 63;
    int run1 = 8 - kq;
    int G, F;
    if (jblk < run1) { G = 7 - kq; F = jblk; } else { G = kq; F = jblk - run1; }
    int f = F * 8 + (i >> 3), g = G * 8 + (i & 7);
    float v = L[f * 64 + g];
    if (F != G) v += L[g * 64 + f];
    Wp[(kq * 18 + j) * 2048 + nt * 512 + (q * 16 + r16) * 8 + el] = bf_rne(v);
  }
}

// ---- quad: r15 body UNCHANGED except blockIdx -> (blockIdx & 255). ----
// Launched with grid = 256*DUP: duplicates recompute the same tile bit-identically
// (jbase from bb -> same accumulation order) and store the same bytes. This is the
// codegen-faithful probe: same registers, same instruction stream as production.
__global__ __launch_bounds__(512) __attribute__((amdgpu_waves_per_eu(2, 2)))
void quad_kernel(const float* __restrict__ x,
                 const unsigned short* __restrict__ Wp,
                 float* __restrict__ out) {
  __shared__ float xT[8192];                 // [f 64][px 128], word = f*128 + (px^f)
  __shared__ alignas(16) float red[16384];   // 16 regions x 4 KB

  const int bb = blockIdx.x & 255;           // pixel-tile id (duplicate-invariant)
  const int t = threadIdx.x;
  const int lane = t & 63;
  const int wv = t >> 6;        // 0..7
  const int kq = wv & 3;        // K quarter
  const int ph = wv >> 2;       // pixel half
  const int q = lane >> 4;
  const int r16 = lane & 15;
  const int pxbase = bb * 128;

  // sweep start: block rotation (r13) + ph offset (r14) — from bb, so duplicates
  // accumulate in the SAME order (bit-identical output)
  int jbase = bb % NCH + ph * (NCH / 2);
  if (jbase >= NCH) jbase -= NCH;

  const char* wsrc = reinterpret_cast<const char*>(Wp) + kq * 73728 + lane * 16;
  const int run1 = 8 - kq;

  auto Gof = [&](int je) { return ((je >> 1) < run1) ? (7 - kq) : kq; };

  bf16x8 bufs[4][4];
  auto loadB = [&](int je, int slot) {
#pragma unroll
    for (int nt = 0; nt < 4; ++nt)
      bufs[slot][nt] = *reinterpret_cast<const bf16x8*>(wsrc + je * 4096 + nt * 1024);
  };
  {
    int je = jbase;
    loadB(je, 0); je = (je + 1 == NCH) ? 0 : je + 1;
    loadB(je, 1); je = (je + 1 == NCH) ? 0 : je + 1;
    loadB(je, 2);
  }

  // x tile -> xT (transposed, XOR word-swizzle; verified r3-r15)
  {
    const float* xg_ = x + (long)pxbase * 64;
#pragma unroll
    for (int c = 0; c < 4; ++c) {
      int e4 = c * 512 + t;
      int px = e4 >> 4;            // 0..127
      int f0 = (e4 & 15) * 4;
      float4 v = *reinterpret_cast<const float4*>(xg_ + e4 * 4);
      xT[(f0 + 0) * 128 + (px ^ (f0 + 0))] = v.x;
      xT[(f0 + 1) * 128 + (px ^ (f0 + 1))] = v.y;
      xT[(f0 + 2) * 128 + (px ^ (f0 + 2))] = v.z;
      xT[(f0 + 3) * 128 + (px ^ (f0 + 3))] = v.w;
    }
  }
  __syncthreads();

  float xg[4][8];
  auto load_xg = [&](int G) {
#pragma unroll
    for (int m = 0; m < 4; ++m) {
      int px = ph * 64 + m * 16 + r16;
#pragma unroll
      for (int b = 0; b < 8; ++b) {
        int row = G * 8 + b;
        xg[m][b] = xT[row * 128 + (px ^ row)];
      }
    }
  };
  int curG = Gof(jbase);
  load_xg(curG);

  f32x4 acc[4][4] = {};   // [m: 4x16 px][nt: 4x16 o]

  int je = jbase;
#pragma unroll
  for (int j = 0; j < NCH; ++j) {
    {
      int jp = je + 3;
      if (jp >= NCH) jp -= NCH;
      if (j + 3 < NCH) loadB(jp, (j + 3) & 3);   // 4-slot ring, lead = 3 bodies
    }
    int G = Gof(je);
    if (G != curG) { curG = G; load_xg(G); }     // wave-uniform, <=3 reloads total
    const int s = je & 1;
    const int blk = je >> 1;
    const int F = (blk < run1) ? blk : blk - run1;
    const int row = F * 8 + s * 4 + q;
    const int slot = j & 3;
    bf16x8 afr[4];
#pragma unroll
    for (int m = 0; m < 4; ++m) {
      float xf = xT[row * 128 + ((ph * 64 + m * 16 + r16) ^ row)];
      union { unsigned u[4]; bf16x8 v; } pk;
#pragma unroll
      for (int i = 0; i < 4; ++i) {
        unsigned p0 = __float_as_uint(xf * xg[m][2 * i]);
        unsigned p1 = __float_as_uint(xf * xg[m][2 * i + 1]);
        pk.u[i] = __builtin_amdgcn_perm(p1, p0, 0x07060302u);   // truncate-pack 2x bf16
      }
      afr[m] = pk.v;
    }
#pragma unroll
    for (int nt = 0; nt < 4; ++nt)
#pragma unroll
      for (int m = 0; m < 4; ++m)
        acc[m][nt] = __builtin_amdgcn_mfma_f32_16x16x32_bf16(afr[m], bufs[slot][nt],
                                                             acc[m][nt], 0, 0, 0);
    je = (je + 1 == NCH) ? 0 : je + 1;
  }

  // ---- cross-kq reduction (verbatim r8): 2 rounds of m-pairs ----
#pragma unroll
  for (int r = 0; r < 2; ++r) {
    if (r) __syncthreads();
#pragma unroll
    for (int mm = 0; mm < 2; ++mm)
#pragma unroll
      for (int nt = 0; nt < 4; ++nt)
        *reinterpret_cast<f32x4*>(red + ((ph * 2 + mm) * 4 + kq) * 1024 +
                                  (nt * 16 + r16) * 16 + q * 4) = acc[2 * r + mm][nt];
    __syncthreads();
    {
      const int mm2 = kq >> 1;
      const int h = kq & 1;
      const float* base = red + (ph * 2 + mm2) * 4 * 1024;
#pragma unroll
      for (int nh = 0; nh < 2; ++nh) {
        int nt = h * 2 + nh;
        int off = (nt * 16 + r16) * 16 + q * 4;
        f32x4 ssum = *reinterpret_cast<const f32x4*>(base + off);
#pragma unroll
        for (int w = 1; w < 4; ++w)
          ssum += *reinterpret_cast<const f32x4*>(base + w * 1024 + off);
        long prow = pxbase + ph * 64 + (2 * r + mm2) * 16 + q * 4;   // D: row=q*4+b, col=r16
#pragma unroll
        for (int b = 0; b < 4; ++b)
          out[(prow + b) * 64 + nt * 16 + r16] = ssum[b];
      }
    }
  }
}

extern "C" void kernel_launch(void* const* d_in, const int* in_sizes, int n_in,
                              void* d_out, int out_size, void* d_ws, size_t ws_size,
                              hipStream_t stream) {
  const float* x = (const float*)d_in[0];
  const float* W = (const float*)d_in[1];
  float* out = (float*)d_out;
  unsigned short* Wp = (unsigned short*)d_ws;   // 288 KB packed fragment-linear bf16 W

  hipLaunchKernelGGL(wprep_kernel, dim3(64), dim3(256), 0, stream, W, Wp);
  // PROBE: grid-duplicated plain kernel (8x work, bit-identical output).
  hipLaunchKernelGGL(quad_kernel, dim3(256 * DUP), dim3(512), 0, stream, x, Wp, out);
}

// Round 18
// 23.511 us; speedup vs baseline: 19.6133x; 4.5492x over previous
//
#include <hip/hip_runtime.h>

typedef __attribute__((ext_vector_type(8))) short bf16x8;
typedef __attribute__((ext_vector_type(4))) float f32x4;

constexpr int NCH = 18;     // 32-k chunks per K-quarter (K = 2304 symmetrized)

__device__ __forceinline__ unsigned short bf_rne(float f) {
  unsigned u = __float_as_uint(f);
  return (unsigned short)((u + 0x7fffu + ((u >> 16) & 1u)) >> 16);
}

// ---- prepass (coalesced, spread over 256 blocks): block = (o, kq) ----
// Wp layout unchanged (verified r5-r17): Wp[(kq*18+j)*2048 + nt*512 + (q*16+r16)*8 + el]
__global__ __launch_bounds__(256) void wprep_kernel(const float* __restrict__ W,
                                                    unsigned short* __restrict__ Wp) {
  __shared__ float L[4096];                 // one W row (o fixed), 16 KB
  const int o = blockIdx.x >> 2;            // 0..63
  const int kq = blockIdx.x & 3;            // 0..3
  const int t = threadIdx.x;
  const float4* src = reinterpret_cast<const float4*>(W + o * 4096);
#pragma unroll
  for (int c = 0; c < 4; ++c)
    *reinterpret_cast<float4*>(&L[(c * 256 + t) * 4]) = src[c * 256 + t];
  __syncthreads();
  const int nt = o >> 4, r16 = o & 15;
#pragma unroll
  for (int it = 0; it < 3; ++it) {
    int kl = it * 256 + t;                  // k within quarter
    if (kl < 576) {
      int j = kl >> 5;
      int q = (kl >> 3) & 3;
      int el = kl & 7;
      int jblk = kl >> 6, i = kl & 63;
      int run1 = 8 - kq;
      int G, F;
      if (jblk < run1) { G = 7 - kq; F = jblk; } else { G = kq; F = jblk - run1; }
      int f = F * 8 + (i >> 3), g = G * 8 + (i & 7);
      float v = L[f * 64 + g];
      if (F != G) v += L[g * 64 + f];
      Wp[(kq * 18 + j) * 2048 + nt * 512 + (q * 16 + r16) * 8 + el] = bf_rne(v);
    }
  }
}

// xT swizzle: px^row spreads r16 lanes; ^((row&3)<<4) splits q-groups across
// bank halves -> xf reads 2-way (free). Bijective within each 64-word row.
__device__ __forceinline__ int xidx(int row, int px) {
  return row * 64 + (px ^ row ^ ((row & 3) << 4));
}

// ---- main quad: 512 blocks x 512 thr (8 waves = 2 ph x 4 kq), 64 px/block ----
// 2 blocks/CU (4 waves/SIMD): VGPR <=128 (m=2 acc, 2-slot B ring), LDS 51 KB.
__global__ __launch_bounds__(512) __attribute__((amdgpu_waves_per_eu(4, 4)))
void quad_kernel(const float* __restrict__ x,
                 const unsigned short* __restrict__ Wp,
                 float* __restrict__ out) {
  __shared__ float xT[4096];                       // [64f][64px] swizzled (16 KB)
  __shared__ alignas(16) float red[8 * 16 * 68];   // 8 regions x [px16][o64+4pad] (34 KB)

  const int t = threadIdx.x;
  const int lane = t & 63;
  const int wv = t >> 6;        // 0..7
  const int kq = wv & 3;        // K quarter
  const int ph = wv >> 2;       // pixel half (32 px)
  const int q = lane >> 4;
  const int r16 = lane & 15;
  const int pxbase = blockIdx.x * 64;

  int jbase = blockIdx.x % NCH;              // block rotation (r13, de-lockstep)

  const char* wsrc = reinterpret_cast<const char*>(Wp) + kq * 73728 + lane * 16;
  const int run1 = 8 - kq;
  auto Gof = [&](int je) { return ((je >> 1) < run1) ? (7 - kq) : kq; };

  bf16x8 bufs[2][4];                         // 2-slot ring (32 VGPR), lead = 1 body
  auto loadB = [&](int je, int slot) {
#pragma unroll
    for (int nt = 0; nt < 4; ++nt)
      bufs[slot][nt] = *reinterpret_cast<const bf16x8*>(wsrc + je * 4096 + nt * 1024);
  };
  loadB(jbase, 0);
  {
    int j1 = (jbase + 1 == NCH) ? 0 : jbase + 1;
    loadB(j1, 1);
  }

  // x tile -> xT (transposed, q-spread swizzle; all access classes <=2-way)
  {
    const float* xg_ = x + (long)pxbase * 64;
#pragma unroll
    for (int c = 0; c < 2; ++c) {
      int e4 = c * 512 + t;
      int px = e4 >> 4;            // 0..63
      int f0 = (e4 & 15) * 4;
      float4 v = *reinterpret_cast<const float4*>(xg_ + e4 * 4);
      xT[xidx(f0 + 0, px)] = v.x;
      xT[xidx(f0 + 1, px)] = v.y;
      xT[xidx(f0 + 2, px)] = v.z;
      xT[xidx(f0 + 3, px)] = v.w;
    }
  }
  __syncthreads();

  float xg[2][8];
  auto load_xg = [&](int G) {
#pragma unroll
    for (int m = 0; m < 2; ++m) {
      int px = ph * 32 + m * 16 + r16;
#pragma unroll
      for (int b = 0; b < 8; ++b)
        xg[m][b] = xT[xidx(G * 8 + b, px)];   // broadcast groups, conflict-free
    }
  };
  int curG = Gof(jbase);
  load_xg(curG);

  f32x4 acc[2][4] = {};   // [m: 2x16 px][nt: 4x16 o]

  int je = jbase;
#pragma unroll
  for (int j = 0; j < NCH; ++j) {
    if (j + 1 < NCH) {                       // refill freed slot (lead = 1 body)
      int jn = je + 1;
      if (jn >= NCH) jn -= NCH;
      loadB(jn, (j + 1) & 1);
    }
    int G = Gof(je);
    if (G != curG) { curG = G; load_xg(G); } // wave-uniform, <=2 reloads
    const int s = je & 1;
    const int blk = je >> 1;
    const int F = (blk < run1) ? blk : blk - run1;
    const int row = F * 8 + s * 4 + q;
    const int slot = j & 1;
#pragma unroll
    for (int m = 0; m < 2; ++m) {
      float xf = xT[xidx(row, ph * 32 + m * 16 + r16)];
      union { unsigned u[4]; bf16x8 v; } pk;
#pragma unroll
      for (int i = 0; i < 4; ++i) {
        unsigned p0 = __float_as_uint(xf * xg[m][2 * i]);
        unsigned p1 = __float_as_uint(xf * xg[m][2 * i + 1]);
        pk.u[i] = __builtin_amdgcn_perm(p1, p0, 0x07060302u);   // truncate-pack 2x bf16
      }
#pragma unroll
      for (int nt = 0; nt < 4; ++nt)
        acc[m][nt] = __builtin_amdgcn_mfma_f32_16x16x32_bf16(pk.v, bufs[slot][nt],
                                                             acc[m][nt], 0, 0, 0);
    }
    je = (je + 1 == NCH) ? 0 : je + 1;
  }

  // ---- cross-kq reduction: 2 rounds (r = m), conflict-free layouts ----
  // region(ph,kq) = [px16][o 64+4pad]; writes scatter-b32 (2-way), reads b128 (~2-way)
#pragma unroll
  for (int r = 0; r < 2; ++r) {
    if (r) __syncthreads();                  // WAR vs previous round's reads
    {
      float* reg = red + (ph * 4 + kq) * 1088;
#pragma unroll
      for (int nt = 0; nt < 4; ++nt)
#pragma unroll
        for (int b = 0; b < 4; ++b)
          reg[(q * 4 + b) * 68 + nt * 16 + r16] = acc[r][nt][b];
    }
    __syncthreads();
    {
      const int pxi = lane >> 2;             // 0..15
      const int o4 = (lane & 3) * 4;         // 0..12
      const int off = pxi * 68 + kq * 16 + o4;
      const float* base = red + ph * 4 * 1088;
      f32x4 ssum = *reinterpret_cast<const f32x4*>(base + off);
#pragma unroll
      for (int w = 1; w < 4; ++w)
        ssum += *reinterpret_cast<const f32x4*>(base + w * 1088 + off);
      long px = pxbase + ph * 32 + r * 16 + pxi;
      *reinterpret_cast<f32x4*>(out + px * 64 + kq * 16 + o4) = ssum;
    }
  }
}

extern "C" void kernel_launch(void* const* d_in, const int* in_sizes, int n_in,
                              void* d_out, int out_size, void* d_ws, size_t ws_size,
                              hipStream_t stream) {
  const float* x = (const float*)d_in[0];
  const float* W = (const float*)d_in[1];
  float* out = (float*)d_out;
  unsigned short* Wp = (unsigned short*)d_ws;   // 288 KB packed fragment-linear bf16 W

  hipLaunchKernelGGL(wprep_kernel, dim3(256), dim3(256), 0, stream, W, Wp);
  hipLaunchKernelGGL(quad_kernel, dim3(512), dim3(512), 0, stream, x, Wp, out);
}